// Round 12
// baseline (229.150 us; speedup 1.0000x reference)
//
#include <hip/hip_runtime.h>
#include <hip/hip_fp16.h>

#define NN 50000
#define EE 800000
#define DD 96
#define GG 64
#define NH 12    // uint4 (8-half) chunks per 96-half row

#define FPSCALE 16777216.0f           // 2^24 fixed-point for weight sums
#define MASK44 ((1ULL << 44) - 1)
#define NCPY 8   // histogram copies
#define NBG ((NN + 127) / 128)        // 391 gemm blocks (128-row tiles)

typedef unsigned long long u64;

__device__ __forceinline__ uint4 pack8(const float* f) {
    __half2 h0 = __floats2half2_rn(f[0], f[1]);
    __half2 h1 = __floats2half2_rn(f[2], f[3]);
    __half2 h2 = __floats2half2_rn(f[4], f[5]);
    __half2 h3 = __floats2half2_rn(f[6], f[7]);
    uint4 o;
    o.x = *(unsigned int*)&h0; o.y = *(unsigned int*)&h1;
    o.z = *(unsigned int*)&h2; o.w = *(unsigned int*)&h3;
    return o;
}

__device__ __forceinline__ void cvt8(uint4 v, float* f) {
    const __half2* h = (const __half2*)&v;
    #pragma unroll
    for (int k = 0; k < 4; ++k) {
        float2 t = __half22float2(h[k]);
        f[2 * k] = t.x; f[2 * k + 1] = t.y;
    }
}

__device__ __forceinline__ void cvt12(uint2 a, uint2 b, uint2 c,
                                      float4& w0, float4& w1, float4& w2) {
    float2 t0 = __half22float2(*(const __half2*)&a.x);
    float2 t1 = __half22float2(*(const __half2*)&a.y);
    float2 t2 = __half22float2(*(const __half2*)&b.x);
    float2 t3 = __half22float2(*(const __half2*)&b.y);
    float2 t4 = __half22float2(*(const __half2*)&c.x);
    float2 t5 = __half22float2(*(const __half2*)&c.y);
    w0 = make_float4(t0.x, t0.y, t1.x, t1.y);
    w1 = make_float4(t2.x, t2.y, t3.x, t3.y);
    w2 = make_float4(t4.x, t4.y, t5.x, t5.y);
}

__device__ __forceinline__ void fma4(float4& a, float s, const float4 w) {
    a.x = fmaf(s, w.x, a.x); a.y = fmaf(s, w.y, a.y);
    a.z = fmaf(s, w.z, a.z); a.w = fmaf(s, w.w, a.w);
}

// ---------------- pre-pass: zero state + fp16 conversions ----------------

__global__ void k_pre(u64* histo, float* gsum,
                      const float4* __restrict__ x, uint4* __restrict__ xh,
                      const float4* __restrict__ W1, uint4* __restrict__ w1h,
                      const float4* __restrict__ W3, uint4* __restrict__ w3h) {
    int i = blockIdx.x * 256 + threadIdx.x;
    if (i < NCPY * NN) histo[i] = 0ULL;
    if (i < GG * DD) gsum[i] = 0.f;
    if (i < 1152) {
        float4 f0 = W1[2 * i], f1 = W1[2 * i + 1];
        float f[8] = {f0.x, f0.y, f0.z, f0.w, f1.x, f1.y, f1.z, f1.w};
        w1h[i] = pack8(f);
    } else if (i < 2304) {
        int j = i - 1152;
        float4 f0 = W3[2 * j], f1 = W3[2 * j + 1];
        float f[8] = {f0.x, f0.y, f0.z, f0.w, f1.x, f1.y, f1.z, f1.w};
        w3h[j] = pack8(f);
    }
    if (i < NN * DD / 8) {
        float4 f0 = x[2 * i], f1 = x[2 * i + 1];
        float f[8] = {f0.x, f0.y, f0.z, f0.w, f1.x, f1.y, f1.z, f1.w};
        xh[i] = pack8(f);
    }
}

// ---------------- histogram: 1 u64 atomic per edge, 8 copies ----------------

__global__ void k_hist(const int* __restrict__ dst, const float* __restrict__ ew,
                       u64* histo, unsigned int* rank) {
    int e = blockIdx.x * 256 + threadIdx.x;
    int cpy = blockIdx.x & (NCPY - 1);
    if (e < EE) {
        u64 q = (u64)(ew[e] * FPSCALE + 0.5f);
        u64 old = atomicAdd(&histo[(size_t)cpy * NN + dst[e]], (1ULL << 44) | q);
        rank[e] = ((unsigned)cpy << 24) | (unsigned)(old >> 44);
    }
}

// ---------------- reduce 8 copies: dinv, per-copy offsets, block count sums ----------------

__global__ __launch_bounds__(256) void k_dinv_reduce(const u64* __restrict__ histo,
                                                     float* dinv, int* cnts,
                                                     unsigned* xoff, int* bsums) {
    __shared__ int s[256];
    int tid = threadIdx.x;
    int i = blockIdx.x * 256 + tid;
    int tot = 0;
    if (i < NN) {
        u64 wsum44 = 0;
        unsigned pre = 0;
        #pragma unroll
        for (int x = 0; x < NCPY; ++x) {
            u64 h = histo[(size_t)x * NN + i];
            wsum44 += h & MASK44;
            xoff[(size_t)i * NCPY + x] = pre;
            pre += (unsigned)(h >> 44);
        }
        tot = (int)pre;
        cnts[i] = tot;
        dinv[i] = rsqrtf(1.0f + (float)wsum44 * (1.0f / FPSCALE));
    }
    s[tid] = tot;
    __syncthreads();
    for (int off = 128; off > 0; off >>= 1) {
        if (tid < off) s[tid] += s[tid + off];
        __syncthreads();
    }
    if (tid == 0) bsums[blockIdx.x] = s[0];
}

// ---------------- merged scan ----------------

__global__ __launch_bounds__(256) void k_scan2(const int* __restrict__ cnts,
                                               const int* __restrict__ bsums,
                                               int nb, int* row_ptr) {
    __shared__ int s[256];
    int tid = threadIdx.x;
    int bv = (tid < nb) ? bsums[tid] : 0;
    s[tid] = bv; __syncthreads();
    for (int off = 1; off < 256; off <<= 1) {
        int t = (tid >= off) ? s[tid - off] : 0;
        __syncthreads();
        s[tid] += t;
        __syncthreads();
    }
    int pb = (blockIdx.x > 0) ? s[blockIdx.x - 1] : 0;
    __syncthreads();
    int i = blockIdx.x * 256 + tid;
    int v = (i < NN) ? cnts[i] : 0;
    s[tid] = v; __syncthreads();
    for (int off = 1; off < 256; off <<= 1) {
        int t = (tid >= off) ? s[tid - off] : 0;
        __syncthreads();
        s[tid] += t;
        __syncthreads();
    }
    if (i < NN) row_ptr[i] = pb + s[tid] - v;
    if (blockIdx.x == gridDim.x - 1 && tid == 255) row_ptr[NN] = EE;
}

// ---------------- scatter (no atomics) ----------------

__global__ void k_scatter(const int* __restrict__ src, const int* __restrict__ dst,
                          const float* __restrict__ ew, const float* __restrict__ dinv,
                          const int* __restrict__ row_ptr, const unsigned* __restrict__ xoff,
                          const unsigned int* __restrict__ rank, int2* csr) {
    int e = blockIdx.x * 256 + threadIdx.x;
    if (e < EE) {
        int s = src[e], d = dst[e];
        unsigned r = rank[e];
        int x = (int)(r >> 24);
        int p = row_ptr[d] + (int)xoff[(size_t)d * NCPY + x] + (int)(r & 0xFFFFFFu);
        float w = dinv[s] * ew[e] * dinv[d];
        csr[p] = make_int2(s, __float_as_int(w));
    }
}

// ---------------- propagation (CSR gather, fp16 in AND out) ----------------

__global__ __launch_bounds__(192) void k_prop_h(const uint4* __restrict__ Th,
                                                const int2* __restrict__ csr,
                                                const int* __restrict__ row_ptr,
                                                const float* __restrict__ dinv,
                                                uint4* __restrict__ Ph) {
    int tid = threadIdx.x;
    int node = blockIdx.x * 16 + tid / 12;
    int c = tid % 12;
    float di = dinv[node];
    float self = di * di;
    float f[8], acc[8];
    cvt8(Th[node * NH + c], f);
    #pragma unroll
    for (int j = 0; j < 8; ++j) acc[j] = self * f[j];
    int e0 = row_ptr[node], e1 = row_ptr[node + 1];
    for (int e = e0; e < e1; ++e) {
        int2 sw = csr[e];
        float w = __int_as_float(sw.y);
        cvt8(Th[sw.x * NH + c], f);
        #pragma unroll
        for (int j = 0; j < 8; ++j) acc[j] = fmaf(w, f[j], acc[j]);
    }
    Ph[node * NH + c] = pack8(acc);
}

// ---------------- GEMM core: 128-row tile, W fp16 in LDS (18 KB) ----------------
// 256 threads = 32 s x 8 cg; 4 rows/thread; A fp16 read direct from global
// (L2 absorbs the 8x re-read — proven round 11: LDS A-staging was null).

#define GEMM_BODY(Xh_, sW_, bias_, base_)                                          \
    int cg = tid & 7, s = tid >> 3;                                                \
    const float4* bv = (const float4*)(bias_) + cg * 3;                            \
    const uint4 *xr0, *xr1, *xr2, *xr3;                                            \
    {                                                                              \
        int r0 = (base_) + s;        int c0 = r0 < NN ? r0 : NN - 1;               \
        int r1 = (base_) + s + 32;   int c1 = r1 < NN ? r1 : NN - 1;               \
        int r2 = (base_) + s + 64;   int c2 = r2 < NN ? r2 : NN - 1;               \
        int r3 = (base_) + s + 96;   int c3 = r3 < NN ? r3 : NN - 1;               \
        xr0 = (Xh_) + (size_t)c0 * NH; xr1 = (Xh_) + (size_t)c1 * NH;              \
        xr2 = (Xh_) + (size_t)c2 * NH; xr3 = (Xh_) + (size_t)c3 * NH;              \
    }                                                                              \
    float4 acc[4][3];                                                              \
    _Pragma("unroll")                                                              \
    for (int j = 0; j < 4; ++j) { acc[j][0] = bv[0]; acc[j][1] = bv[1]; acc[j][2] = bv[2]; } \
    _Pragma("unroll 2")                                                            \
    for (int k12 = 0; k12 < NH; ++k12) {                                           \
        float f0[8], f1[8], f2[8], f3[8];                                          \
        cvt8(xr0[k12], f0); cvt8(xr1[k12], f1);                                    \
        cvt8(xr2[k12], f2); cvt8(xr3[k12], f3);                                    \
        _Pragma("unroll")                                                          \
        for (int kk = 0; kk < 8; ++kk) {                                           \
            const uint2* wr = (const uint2*)(sW_) + (size_t)(k12 * 8 + kk) * 24 + cg * 3; \
            float4 w0, w1, w2;                                                     \
            cvt12(wr[0], wr[1], wr[2], w0, w1, w2);                                \
            fma4(acc[0][0], f0[kk], w0); fma4(acc[0][1], f0[kk], w1); fma4(acc[0][2], f0[kk], w2); \
            fma4(acc[1][0], f1[kk], w0); fma4(acc[1][1], f1[kk], w1); fma4(acc[1][2], f1[kk], w2); \
            fma4(acc[2][0], f2[kk], w0); fma4(acc[2][1], f2[kk], w1); fma4(acc[2][2], f2[kk], w2); \
            fma4(acc[3][0], f3[kk], w0); fma4(acc[3][1], f3[kk], w1); fma4(acc[3][2], f3[kk], w2); \
        }                                                                          \
    }

// ---------------- GEMM layer 1: hh = relu(Xh @ W1 + b1), fp16 out ----------------

__global__ __launch_bounds__(256) void k_gemm1(const uint4* __restrict__ Xh,
                                               const uint4* __restrict__ Wh,
                                               const float* __restrict__ bias,
                                               __half2* __restrict__ Oh) {
    __shared__ uint4 sW[1152];   // 96x96 fp16 = 18 KB
    int tid = threadIdx.x;
    for (int i = tid; i < 1152; i += 256) sW[i] = Wh[i];
    __syncthreads();
    int base = blockIdx.x * 128;
    GEMM_BODY(Xh, sW, bias, base)
    #pragma unroll
    for (int j = 0; j < 4; ++j) {
        int row = base + s + 32 * j;
        if (row >= NN) continue;
        float4 a0 = acc[j][0], a1 = acc[j][1], a2 = acc[j][2];
        a0.x = fmaxf(a0.x, 0.f); a0.y = fmaxf(a0.y, 0.f); a0.z = fmaxf(a0.z, 0.f); a0.w = fmaxf(a0.w, 0.f);
        a1.x = fmaxf(a1.x, 0.f); a1.y = fmaxf(a1.y, 0.f); a1.z = fmaxf(a1.z, 0.f); a1.w = fmaxf(a1.w, 0.f);
        a2.x = fmaxf(a2.x, 0.f); a2.y = fmaxf(a2.y, 0.f); a2.z = fmaxf(a2.z, 0.f); a2.w = fmaxf(a2.w, 0.f);
        __half2* o = Oh + ((size_t)row * DD + cg * 12) / 2;
        o[0] = __floats2half2_rn(a0.x, a0.y);
        o[1] = __floats2half2_rn(a0.z, a0.w);
        o[2] = __floats2half2_rn(a1.x, a1.y);
        o[3] = __floats2half2_rn(a1.z, a1.w);
        o[4] = __floats2half2_rn(a2.x, a2.y);
        o[5] = __floats2half2_rn(a2.z, a2.w);
    }
}

// ---------------- tail: gemm2 (embed, f32) + pool stage A in ONE dispatch ----------------

__global__ __launch_bounds__(384) void k_tail(const uint4* __restrict__ Ph,
                                              const uint4* __restrict__ W3h,
                                              const float* __restrict__ b3,
                                              float* __restrict__ embed,
                                              const int* __restrict__ batch,
                                              float* __restrict__ gsum) {
    int tid = threadIdx.x;
    if (blockIdx.x < NBG) {
        __shared__ uint4 sW[1152];   // 18 KB
        for (int i = tid; i < 1152; i += 384) sW[i] = W3h[i];
        __syncthreads();
        if (tid >= 256) return;
        int base = blockIdx.x * 128;
        GEMM_BODY(Ph, sW, b3, base)
        #pragma unroll
        for (int j = 0; j < 4; ++j) {
            int row = base + s + 32 * j;
            if (row >= NN) continue;
            float4* o = (float4*)(embed + (size_t)row * DD + cg * 12);
            o[0] = acc[j][0]; o[1] = acc[j][1]; o[2] = acc[j][2];
        }
    } else {
        const __half* P2 = (const __half*)Ph;
        int b = blockIdx.x - NBG;
        int g = b >> 3, s = b & 7;
        int d = tid % 96, t = tid / 96;
        int lo = 0, hi = NN;
        while (lo < hi) { int m = (lo + hi) >> 1; if (batch[m] < g) lo = m + 1; else hi = m; }
        int start = lo;
        lo = 0; hi = NN;
        while (lo < hi) { int m = (lo + hi) >> 1; if (batch[m] < g + 1) lo = m + 1; else hi = m; }
        int end = lo;
        float acc = 0.f;
        for (int i = start + s * 4 + t; i < end; i += 32)
            acc += __half2float(P2[(size_t)i * DD + d]);
        __shared__ float red[384];
        red[tid] = acc;
        __syncthreads();
        if (tid < 96) {
            float v = red[tid] + red[tid + 96] + red[tid + 192] + red[tid + 288];
            atomicAdd(&gsum[g * 96 + tid], v);
        }
    }
}

// ---------------- pool stage B: outG = gsum @ W4 + cnt * b4 ----------------

__global__ __launch_bounds__(96) void k_pool_b(const float* __restrict__ gsum,
                                               const int* __restrict__ batch,
                                               const float* __restrict__ W4,
                                               const float* __restrict__ b4,
                                               float* __restrict__ outG) {
    int g = blockIdx.x, d = threadIdx.x;
    __shared__ float srow[96];
    srow[d] = gsum[g * 96 + d];
    int lo = 0, hi = NN;
    while (lo < hi) { int m = (lo + hi) >> 1; if (batch[m] < g) lo = m + 1; else hi = m; }
    int start = lo;
    lo = 0; hi = NN;
    while (lo < hi) { int m = (lo + hi) >> 1; if (batch[m] < g + 1) lo = m + 1; else hi = m; }
    int end = lo;
    __syncthreads();
    float o = (float)(end - start) * b4[d];
    #pragma unroll 8
    for (int k = 0; k < 96; ++k) o = fmaf(srow[k], W4[k * 96 + d], o);
    outG[g * 96 + d] = o;
}

// ---------------- launch ----------------

extern "C" void kernel_launch(void* const* d_in, const int* in_sizes, int n_in,
                              void* d_out, int out_size, void* d_ws, size_t ws_size,
                              hipStream_t stream) {
    const float* x  = (const float*)d_in[0];
    const float* W1 = (const float*)d_in[1];
    const float* b1 = (const float*)d_in[2];
    const float* W3 = (const float*)d_in[3];
    const float* b3 = (const float*)d_in[4];
    const float* W4 = (const float*)d_in[5];
    const float* b4 = (const float*)d_in[6];
    const float* ew = (const float*)d_in[7];
    const int* ei   = (const int*)d_in[8];
    const int* src  = ei;
    const int* dst  = ei + EE;
    const int* batch = (const int*)d_in[9];

    float* out_embed = (float*)d_out;
    float* out_graph = out_embed + (size_t)NN * DD;

    char* w = (char*)d_ws;
    auto alloc = [&](size_t bytes) { char* p = w; w += (bytes + 255) & ~(size_t)255; return p; };
    u64* histo     = (u64*)  alloc((size_t)NCPY * NN * 8);
    unsigned* rank = (unsigned*)alloc((size_t)EE * 4);
    float* dinv    = (float*)alloc((size_t)NN * 4);
    int*   cnts    = (int*)  alloc((size_t)NN * 4);
    unsigned* xoff = (unsigned*)alloc((size_t)NN * NCPY * 4);
    int*   row_ptr = (int*)  alloc((size_t)(NN + 1) * 4);
    int*   bsums   = (int*)  alloc(256 * 4);
    float* gsum    = (float*)alloc((size_t)GG * DD * 4);
    int2*  csr     = (int2*) alloc((size_t)EE * 8);
    uint4* xh      = (uint4*)alloc((size_t)NN * DD * 2);   // fp16 x
    uint4* hh      = (uint4*)alloc((size_t)NN * DD * 2);   // fp16 h
    uint4* ph      = (uint4*)alloc((size_t)NN * DD * 2);   // fp16 P1, reused as P2
    uint4* w1h     = (uint4*)alloc(1152 * 16);             // fp16 W1
    uint4* w3h     = (uint4*)alloc(1152 * 16);             // fp16 W3

    int nbN = (NN + 255) / 256;       // 196
    int nbE = (EE + 255) / 256;       // 3125
    int nbP = (NN * DD / 8 + 255) / 256;

    k_pre<<<nbP, 256, 0, stream>>>(histo, gsum, (const float4*)x, xh,
                                   (const float4*)W1, w1h, (const float4*)W3, w3h);
    k_hist<<<nbE, 256, 0, stream>>>(dst, ew, histo, rank);
    k_dinv_reduce<<<nbN, 256, 0, stream>>>(histo, dinv, cnts, xoff, bsums);
    k_scan2<<<nbN, 256, 0, stream>>>(cnts, bsums, nbN, row_ptr);
    k_scatter<<<nbE, 256, 0, stream>>>(src, dst, ew, dinv, row_ptr, xoff, rank, csr);

    // P1 = A_hat @ x [fp16] ; h = relu(P1 @ W1 + b1) [fp16]
    k_prop_h<<<NN / 16, 192, 0, stream>>>(xh, csr, row_ptr, dinv, ph);
    k_gemm1<<<NBG, 256, 0, stream>>>(ph, w1h, b1, (__half2*)hh);
    // P2 = A_hat @ h [fp16] ; {embed = P2 @ W3 + b3} ∥ {pool partials}
    k_prop_h<<<NN / 16, 192, 0, stream>>>(hh, csr, row_ptr, dinv, ph);
    k_tail<<<NBG + GG * 8, 384, 0, stream>>>(ph, w3h, b3, out_embed, batch, gsum);
    k_pool_b<<<GG, 96, 0, stream>>>(gsum, batch, W4, b4, out_graph);
}

// Round 13
// 189.992 us; speedup vs baseline: 1.2061x; 1.2061x over previous
//
#include <hip/hip_runtime.h>
#include <hip/hip_fp16.h>

#define NN 50000
#define EE 800000
#define DD 96
#define GG 64
#define NH 12    // uint4 (8-half) chunks per 96-half row
#define NT 3125  // 16-row MFMA tiles (50000/16 exactly)

#define FPSCALE 16777216.0f           // 2^24 fixed-point for weight sums
#define MASK44 ((1ULL << 44) - 1)
#define NCPY 8   // histogram copies
#define NBG2 ((NT + 3) / 4)           // 782 gemm blocks (4 waves x 16 rows)

typedef unsigned long long u64;
typedef __attribute__((ext_vector_type(8))) _Float16 half8;
typedef __attribute__((ext_vector_type(4))) float f32x4;

__device__ __forceinline__ uint4 pack8(const float* f) {
    __half2 h0 = __floats2half2_rn(f[0], f[1]);
    __half2 h1 = __floats2half2_rn(f[2], f[3]);
    __half2 h2 = __floats2half2_rn(f[4], f[5]);
    __half2 h3 = __floats2half2_rn(f[6], f[7]);
    uint4 o;
    o.x = *(unsigned int*)&h0; o.y = *(unsigned int*)&h1;
    o.z = *(unsigned int*)&h2; o.w = *(unsigned int*)&h3;
    return o;
}

__device__ __forceinline__ void cvt8(uint4 v, float* f) {
    const __half2* h = (const __half2*)&v;
    #pragma unroll
    for (int k = 0; k < 4; ++k) {
        float2 t = __half22float2(h[k]);
        f[2 * k] = t.x; f[2 * k + 1] = t.y;
    }
}

// ---------------- pre-pass: zero state + fp16 conversions + W transposes ----------------

__global__ void k_pre(u64* histo, float* gsum,
                      const float4* __restrict__ x, uint4* __restrict__ xh,
                      const float* __restrict__ W1, _Float16* __restrict__ w1t,
                      const float* __restrict__ W3, _Float16* __restrict__ w3t) {
    int i = blockIdx.x * 256 + threadIdx.x;
    if (i < NCPY * NN) histo[i] = 0ULL;
    if (i < GG * DD) gsum[i] = 0.f;
    if (i < DD * DD) {              // Wt[n][k] = W[k][n], fp16
        int k = i / DD, n = i % DD;
        w1t[n * DD + k] = (_Float16)W1[i];
        w3t[n * DD + k] = (_Float16)W3[i];
    }
    if (i < NN * DD / 8) {
        float4 f0 = x[2 * i], f1 = x[2 * i + 1];
        float f[8] = {f0.x, f0.y, f0.z, f0.w, f1.x, f1.y, f1.z, f1.w};
        xh[i] = pack8(f);
    }
}

// ---------------- histogram: 1 u64 atomic per edge, 8 copies ----------------

__global__ void k_hist(const int* __restrict__ dst, const float* __restrict__ ew,
                       u64* histo, unsigned int* rank) {
    int e = blockIdx.x * 256 + threadIdx.x;
    int cpy = blockIdx.x & (NCPY - 1);
    if (e < EE) {
        u64 q = (u64)(ew[e] * FPSCALE + 0.5f);
        u64 old = atomicAdd(&histo[(size_t)cpy * NN + dst[e]], (1ULL << 44) | q);
        rank[e] = ((unsigned)cpy << 24) | (unsigned)(old >> 44);
    }
}

// ---------------- reduce 8 copies: dinv, per-copy offsets, block count sums ----------------

__global__ __launch_bounds__(256) void k_dinv_reduce(const u64* __restrict__ histo,
                                                     float* dinv, int* cnts,
                                                     unsigned* xoff, int* bsums) {
    __shared__ int s[256];
    int tid = threadIdx.x;
    int i = blockIdx.x * 256 + tid;
    int tot = 0;
    if (i < NN) {
        u64 wsum44 = 0;
        unsigned pre = 0;
        #pragma unroll
        for (int x = 0; x < NCPY; ++x) {
            u64 h = histo[(size_t)x * NN + i];
            wsum44 += h & MASK44;
            xoff[(size_t)i * NCPY + x] = pre;
            pre += (unsigned)(h >> 44);
        }
        tot = (int)pre;
        cnts[i] = tot;
        dinv[i] = rsqrtf(1.0f + (float)wsum44 * (1.0f / FPSCALE));
    }
    s[tid] = tot;
    __syncthreads();
    for (int off = 128; off > 0; off >>= 1) {
        if (tid < off) s[tid] += s[tid + off];
        __syncthreads();
    }
    if (tid == 0) bsums[blockIdx.x] = s[0];
}

// ---------------- merged scan ----------------

__global__ __launch_bounds__(256) void k_scan2(const int* __restrict__ cnts,
                                               const int* __restrict__ bsums,
                                               int nb, int* row_ptr) {
    __shared__ int s[256];
    int tid = threadIdx.x;
    int bv = (tid < nb) ? bsums[tid] : 0;
    s[tid] = bv; __syncthreads();
    for (int off = 1; off < 256; off <<= 1) {
        int t = (tid >= off) ? s[tid - off] : 0;
        __syncthreads();
        s[tid] += t;
        __syncthreads();
    }
    int pb = (blockIdx.x > 0) ? s[blockIdx.x - 1] : 0;
    __syncthreads();
    int i = blockIdx.x * 256 + tid;
    int v = (i < NN) ? cnts[i] : 0;
    s[tid] = v; __syncthreads();
    for (int off = 1; off < 256; off <<= 1) {
        int t = (tid >= off) ? s[tid - off] : 0;
        __syncthreads();
        s[tid] += t;
        __syncthreads();
    }
    if (i < NN) row_ptr[i] = pb + s[tid] - v;
    if (blockIdx.x == gridDim.x - 1 && tid == 255) row_ptr[NN] = EE;
}

// ---------------- scatter (no atomics) ----------------

__global__ void k_scatter(const int* __restrict__ src, const int* __restrict__ dst,
                          const float* __restrict__ ew, const float* __restrict__ dinv,
                          const int* __restrict__ row_ptr, const unsigned* __restrict__ xoff,
                          const unsigned int* __restrict__ rank, int2* csr) {
    int e = blockIdx.x * 256 + threadIdx.x;
    if (e < EE) {
        int s = src[e], d = dst[e];
        unsigned r = rank[e];
        int x = (int)(r >> 24);
        int p = row_ptr[d] + (int)xoff[(size_t)d * NCPY + x] + (int)(r & 0xFFFFFFu);
        float w = dinv[s] * ew[e] * dinv[d];
        csr[p] = make_int2(s, __float_as_int(w));
    }
}

// ---------------- propagation (CSR gather, fp16 in AND out) ----------------

__global__ __launch_bounds__(192) void k_prop_h(const uint4* __restrict__ Th,
                                                const int2* __restrict__ csr,
                                                const int* __restrict__ row_ptr,
                                                const float* __restrict__ dinv,
                                                uint4* __restrict__ Ph) {
    int tid = threadIdx.x;
    int node = blockIdx.x * 16 + tid / 12;
    int c = tid % 12;
    float di = dinv[node];
    float self = di * di;
    float f[8], acc[8];
    cvt8(Th[node * NH + c], f);
    #pragma unroll
    for (int j = 0; j < 8; ++j) acc[j] = self * f[j];
    int e0 = row_ptr[node], e1 = row_ptr[node + 1];
    for (int e = e0; e < e1; ++e) {
        int2 sw = csr[e];
        float w = __int_as_float(sw.y);
        cvt8(Th[sw.x * NH + c], f);
        #pragma unroll
        for (int j = 0; j < 8; ++j) acc[j] = fmaf(w, f[j], acc[j]);
    }
    Ph[node * NH + c] = pack8(acc);
}

// ---------------- MFMA GEMM: one wave = 16 rows x 96 cols, K=96 ----------------
// A-frag: lane reads X[tile*16 + (lane&15)][ks*32 + (lane>>4)*8 ..+8) (16B contig).
// B-frag: lane reads Wt[nt*16 + (lane&15)][ks*32 + (lane>>4)*8 ..+8) (16B contig);
//         all 18 held in VGPRs for the whole wave.
// D: col = lane&15, row = (lane>>4)*4 + reg  [m89, dtype-independent].

__global__ __launch_bounds__(256) void k_gemm1(const _Float16* __restrict__ Xh,
                                               const _Float16* __restrict__ Wt,
                                               const float* __restrict__ bias,
                                               _Float16* __restrict__ Oh) {
    int wv = threadIdx.x >> 6;
    int lane = threadIdx.x & 63;
    int tile = blockIdx.x * 4 + wv;
    if (tile >= NT) return;
    int r = lane & 15, q = lane >> 4;
    half8 bf[3][6];
    #pragma unroll
    for (int ks = 0; ks < 3; ++ks)
        #pragma unroll
        for (int nt = 0; nt < 6; ++nt)
            bf[ks][nt] = *(const half8*)&Wt[(size_t)(nt * 16 + r) * DD + ks * 32 + q * 8];
    f32x4 acc[6];
    #pragma unroll
    for (int nt = 0; nt < 6; ++nt) { float b = bias[nt * 16 + r]; acc[nt] = (f32x4){b, b, b, b}; }
    size_t rowoff = (size_t)(tile * 16 + r) * DD;
    #pragma unroll
    for (int ks = 0; ks < 3; ++ks) {
        half8 af = *(const half8*)&Xh[rowoff + ks * 32 + q * 8];
        #pragma unroll
        for (int nt = 0; nt < 6; ++nt)
            acc[nt] = __builtin_amdgcn_mfma_f32_16x16x32_f16(af, bf[ks][nt], acc[nt], 0, 0, 0);
    }
    int rowbase = tile * 16 + q * 4;
    #pragma unroll
    for (int nt = 0; nt < 6; ++nt)
        #pragma unroll
        for (int g = 0; g < 4; ++g) {
            float v = fmaxf(acc[nt][g], 0.f);
            Oh[(size_t)(rowbase + g) * DD + nt * 16 + r] = (_Float16)v;
        }
}

// ---------------- tail: MFMA gemm2 (embed, f32) + pool stage A, one dispatch ----------------
// blocks [0, NBG2): gemm waves. blocks [NBG2, NBG2+512): pool partials (256 thr).

__global__ __launch_bounds__(256) void k_tail(const _Float16* __restrict__ Ph,
                                              const _Float16* __restrict__ Wt,
                                              const float* __restrict__ b3,
                                              float* __restrict__ embed,
                                              const int* __restrict__ batch,
                                              float* __restrict__ gsum) {
    int tid = threadIdx.x;
    if (blockIdx.x < NBG2) {
        int wv = tid >> 6;
        int lane = tid & 63;
        int tile = blockIdx.x * 4 + wv;
        if (tile >= NT) return;
        int r = lane & 15, q = lane >> 4;
        half8 bf[3][6];
        #pragma unroll
        for (int ks = 0; ks < 3; ++ks)
            #pragma unroll
            for (int nt = 0; nt < 6; ++nt)
                bf[ks][nt] = *(const half8*)&Wt[(size_t)(nt * 16 + r) * DD + ks * 32 + q * 8];
        f32x4 acc[6];
        #pragma unroll
        for (int nt = 0; nt < 6; ++nt) { float b = b3[nt * 16 + r]; acc[nt] = (f32x4){b, b, b, b}; }
        size_t rowoff = (size_t)(tile * 16 + r) * DD;
        #pragma unroll
        for (int ks = 0; ks < 3; ++ks) {
            half8 af = *(const half8*)&Ph[rowoff + ks * 32 + q * 8];
            #pragma unroll
            for (int nt = 0; nt < 6; ++nt)
                acc[nt] = __builtin_amdgcn_mfma_f32_16x16x32_f16(af, bf[ks][nt], acc[nt], 0, 0, 0);
        }
        int rowbase = tile * 16 + q * 4;
        #pragma unroll
        for (int nt = 0; nt < 6; ++nt)
            #pragma unroll
            for (int g = 0; g < 4; ++g)
                embed[(size_t)(rowbase + g) * DD + nt * 16 + r] = acc[nt][g];
    } else {
        const __half* P2 = (const __half*)Ph;
        int b = blockIdx.x - NBG2;
        int g = b >> 3, s = b & 7;
        int d = tid % 96, t = tid / 96;          // t in {0,1} for tid<192
        int lo = 0, hi = NN;
        while (lo < hi) { int m = (lo + hi) >> 1; if (batch[m] < g) lo = m + 1; else hi = m; }
        int start = lo;
        lo = 0; hi = NN;
        while (lo < hi) { int m = (lo + hi) >> 1; if (batch[m] < g + 1) lo = m + 1; else hi = m; }
        int end = lo;
        float acc = 0.f;
        if (tid < 192)
            for (int i = start + s * 2 + t; i < end; i += 16)
                acc += __half2float(P2[(size_t)i * DD + d]);
        __shared__ float red[192];
        if (tid < 192) red[tid] = acc;
        __syncthreads();
        if (tid < 96) atomicAdd(&gsum[g * 96 + tid], red[tid] + red[tid + 96]);
    }
}

// ---------------- pool stage B: outG = gsum @ W4 + cnt * b4 ----------------

__global__ __launch_bounds__(96) void k_pool_b(const float* __restrict__ gsum,
                                               const int* __restrict__ batch,
                                               const float* __restrict__ W4,
                                               const float* __restrict__ b4,
                                               float* __restrict__ outG) {
    int g = blockIdx.x, d = threadIdx.x;
    __shared__ float srow[96];
    srow[d] = gsum[g * 96 + d];
    int lo = 0, hi = NN;
    while (lo < hi) { int m = (lo + hi) >> 1; if (batch[m] < g) lo = m + 1; else hi = m; }
    int start = lo;
    lo = 0; hi = NN;
    while (lo < hi) { int m = (lo + hi) >> 1; if (batch[m] < g + 1) lo = m + 1; else hi = m; }
    int end = lo;
    __syncthreads();
    float o = (float)(end - start) * b4[d];
    #pragma unroll 8
    for (int k = 0; k < 96; ++k) o = fmaf(srow[k], W4[k * 96 + d], o);
    outG[g * 96 + d] = o;
}

// ---------------- launch ----------------

extern "C" void kernel_launch(void* const* d_in, const int* in_sizes, int n_in,
                              void* d_out, int out_size, void* d_ws, size_t ws_size,
                              hipStream_t stream) {
    const float* x  = (const float*)d_in[0];
    const float* W1 = (const float*)d_in[1];
    const float* b1 = (const float*)d_in[2];
    const float* W3 = (const float*)d_in[3];
    const float* b3 = (const float*)d_in[4];
    const float* W4 = (const float*)d_in[5];
    const float* b4 = (const float*)d_in[6];
    const float* ew = (const float*)d_in[7];
    const int* ei   = (const int*)d_in[8];
    const int* src  = ei;
    const int* dst  = ei + EE;
    const int* batch = (const int*)d_in[9];

    float* out_embed = (float*)d_out;
    float* out_graph = out_embed + (size_t)NN * DD;

    char* w = (char*)d_ws;
    auto alloc = [&](size_t bytes) { char* p = w; w += (bytes + 255) & ~(size_t)255; return p; };
    u64* histo     = (u64*)  alloc((size_t)NCPY * NN * 8);
    unsigned* rank = (unsigned*)alloc((size_t)EE * 4);
    float* dinv    = (float*)alloc((size_t)NN * 4);
    int*   cnts    = (int*)  alloc((size_t)NN * 4);
    unsigned* xoff = (unsigned*)alloc((size_t)NN * NCPY * 4);
    int*   row_ptr = (int*)  alloc((size_t)(NN + 1) * 4);
    int*   bsums   = (int*)  alloc(256 * 4);
    float* gsum    = (float*)alloc((size_t)GG * DD * 4);
    int2*  csr     = (int2*) alloc((size_t)EE * 8);
    char*  xh      = alloc((size_t)NN * DD * 2);           // fp16 x
    char*  hh      = alloc((size_t)NN * DD * 2);           // fp16 h
    char*  ph      = alloc((size_t)NN * DD * 2);           // fp16 P1, reused as P2
    _Float16* w1t  = (_Float16*)alloc((size_t)DD * DD * 2);
    _Float16* w3t  = (_Float16*)alloc((size_t)DD * DD * 2);

    int nbN = (NN + 255) / 256;       // 196
    int nbE = (EE + 255) / 256;       // 3125
    int nbP = (NN * DD / 8 + 255) / 256;

    k_pre<<<nbP, 256, 0, stream>>>(histo, gsum, (const float4*)x, (uint4*)xh,
                                   W1, w1t, W3, w3t);
    k_hist<<<nbE, 256, 0, stream>>>(dst, ew, histo, rank);
    k_dinv_reduce<<<nbN, 256, 0, stream>>>(histo, dinv, cnts, xoff, bsums);
    k_scan2<<<nbN, 256, 0, stream>>>(cnts, bsums, nbN, row_ptr);
    k_scatter<<<nbE, 256, 0, stream>>>(src, dst, ew, dinv, row_ptr, xoff, rank, csr);

    // P1 = A_hat @ x [fp16] ; h = relu(P1 @ W1 + b1) [fp16, MFMA]
    k_prop_h<<<NN / 16, 192, 0, stream>>>((const uint4*)xh, csr, row_ptr, dinv, (uint4*)ph);
    k_gemm1<<<NBG2, 256, 0, stream>>>((const _Float16*)ph, w1t, b1, (_Float16*)hh);
    // P2 = A_hat @ h [fp16] ; {embed = P2 @ W3 + b3 [MFMA]} ∥ {pool partials}
    k_prop_h<<<NN / 16, 192, 0, stream>>>((const uint4*)hh, csr, row_ptr, dinv, (uint4*)ph);
    k_tail<<<NBG2 + GG * 8, 256, 0, stream>>>((const _Float16*)ph, w3t, b3, out_embed, batch, gsum);
    k_pool_b<<<GG, 96, 0, stream>>>(gsum, batch, W4, b4, out_graph);
}